// Round 4
// baseline (300.839 us; speedup 1.0000x reference)
//
#include <hip/hip_runtime.h>
#include <hip/hip_bf16.h>
#include <math.h>

// Problem constants (match reference)
constexpr int B = 4, S = 2048, E = 1024, H = 16, D = 64;
constexpr float NEGF = -1000000000.0f;
// scale folded into K pre-pass: 1/sqrt(64) * log2(e)  -> softmax uses exp2
constexpr float KSCALE = 0.125f * 1.44269504f;

typedef __attribute__((ext_vector_type(8))) short short8;   // 8 bf16 = 4 VGPRs
typedef __attribute__((ext_vector_type(16))) float f32x16;  // MFMA 32x32 C/D

// ---------------- helpers ----------------
// fast bf16 pair pack, round-half-up: 2 adds + 1 v_perm (vs ~14-instr RNE)
__device__ inline unsigned pk2(float a, float b) {
    unsigned ua = __builtin_bit_cast(unsigned, a) + 0x8000u;
    unsigned ub = __builtin_bit_cast(unsigned, b) + 0x8000u;
    return __builtin_amdgcn_perm(ub, ua, 0x07060302u);
}
__device__ inline void gl_lds16(const void* g, void* l) {
    __builtin_amdgcn_global_load_lds(
        (const __attribute__((address_space(1))) unsigned int*)g,
        (__attribute__((address_space(3))) unsigned int*)l, 16, 0, 0);
}
// v_permlane32_swap_b32 vdst, vsrc: exchanges vdst's UPPER 32 lanes with
// vsrc's LOWER 32 lanes. After plswap(a,b):
//   lanes 0-31:  a = old a[l]      , b = old a[l+32]
//   lanes 32-63: a = old b[l-32]   , b = old b[l]
// i.e. a = (a_lo, b_lo), b = (a_hi, b_hi) by half-content. (Verified r2.)
__device__ inline void plswap(unsigned& a, unsigned& b) {
    asm volatile("v_permlane32_swap_b32 %0, %1" : "+v"(a), "+v"(b));
}

// ws layout (bytes):
//   Kws  [bh][s][72 bf16]          @ 0          18,874,368   (bf16, *KSCALE)
//   Vtws [bh][kt][64 d][72 bf16]   @ 18874368   18,874,368   (per-tile chunked)
//   Mby  [b][q][tile][64 bytes]    @ 37748736   16,777,216   (0x00/0xFF, permuted)
constexpr size_t WS_K  = 0;
constexpr size_t WS_VT = 18874368;
constexpr size_t WS_MB = 37748736;
constexpr size_t WS_NEED = 54525952;

// ---------------- fused pre-pass: K-cvt, V-transpose, mask-bytes ------------
__global__ void prep_all(const float* __restrict__ K, const float* __restrict__ V,
                         const int* __restrict__ M, char* __restrict__ ws) {
    __shared__ float Vf[64][69];
    const int bid = blockIdx.x, tid = threadIdx.x;

    // ---- K convert: dst row = (b*H+h)*S + s, 72 bf16/row ----
    {
        int g = bid * 256 + tid;
        int rowd = g >> 2, qtr = g & 3;
        int b = rowd >> 15, h = (rowd >> 11) & 15, s = rowd & 2047;
        const float* p = K + ((size_t)(b * S + s)) * E + h * 64 + qtr * 16;
        float4 v0 = *(const float4*)(p + 0),  v1 = *(const float4*)(p + 4);
        float4 v2 = *(const float4*)(p + 8),  v3 = *(const float4*)(p + 12);
        uint4 o0, o1;
        o0.x = pk2(v0.x * KSCALE, v0.y * KSCALE); o0.y = pk2(v0.z * KSCALE, v0.w * KSCALE);
        o0.z = pk2(v1.x * KSCALE, v1.y * KSCALE); o0.w = pk2(v1.z * KSCALE, v1.w * KSCALE);
        o1.x = pk2(v2.x * KSCALE, v2.y * KSCALE); o1.y = pk2(v2.z * KSCALE, v2.w * KSCALE);
        o1.z = pk2(v3.x * KSCALE, v3.y * KSCALE); o1.w = pk2(v3.z * KSCALE, v3.w * KSCALE);
        char* d = ws + WS_K + (size_t)rowd * 144 + qtr * 32;
        *(uint4*)d = o0; *(uint4*)(d + 16) = o1;
        if (qtr == 3) {
            uint4 z; z.x = z.y = z.z = z.w = 0;
            *(uint4*)(d + 32) = z;
        }
    }

    // ---- V transpose: tile (bh,kt) -> 64 d-rows x 72 bf16 ----
    {
        int bh = bid >> 5, kt = bid & 31;
        int b = bh >> 4, h = bh & 15;
        {
            int r = tid >> 2, c4 = (tid & 3) * 16;
            const float* p = V + ((size_t)(b * S + kt * 64 + r)) * E + h * 64 + c4;
            float4 a = *(const float4*)(p + 0), bb = *(const float4*)(p + 4);
            float4 c = *(const float4*)(p + 8), dd = *(const float4*)(p + 12);
            *(float4*)&Vf[r][c4 + 0] = a;  *(float4*)&Vf[r][c4 + 4] = bb;
            *(float4*)&Vf[r][c4 + 8] = c;  *(float4*)&Vf[r][c4 + 12] = dd;
        }
        __syncthreads();
        int d = tid >> 2, sq = (tid & 3) * 16;
        float v[16];
#pragma unroll
        for (int i = 0; i < 16; ++i) v[i] = Vf[sq + i][d];
        uint4 o0, o1;
        o0.x = pk2(v[0], v[1]);   o0.y = pk2(v[2], v[3]);
        o0.z = pk2(v[4], v[5]);   o0.w = pk2(v[6], v[7]);
        o1.x = pk2(v[8], v[9]);   o1.y = pk2(v[10], v[11]);
        o1.z = pk2(v[12], v[13]); o1.w = pk2(v[14], v[15]);
        char* o = ws + WS_VT + ((size_t)(bh * 32 + kt)) * 9216 + d * 144 + sq * 2;
        *(uint4*)o = o0; *(uint4*)(o + 16) = o1;
        if (sq == 48) {
            uint4 z; z.x = z.y = z.z = z.w = 0;
            *(uint4*)(o + 32) = z;
        }
    }

    // ---- mask -> permuted byte-mask (0x00/0xFF per key) ----
    {
        unsigned* Mb = (unsigned*)(ws + WS_MB);
        const int t = bid * 256 + tid;
#pragma unroll
        for (int it = 0; it < 8; ++it) {
            int gidx = it * 524288 + t;
            int4 mv = *((const int4*)M + gidx);
            unsigned d = (mv.x ? 0xFFu : 0u) | (mv.y ? 0xFF00u : 0u)
                       | (mv.z ? 0xFF0000u : 0u) | (mv.w ? 0xFF000000u : 0u);
            int row = gidx >> 4, g = gidx & 15;
            Mb[row * 16 + (g & 1) * 8 + (g >> 1)] = d;
        }
    }
}

// ---------------- main: dedicated-stage structure, 8 blocks/CU ----------------
// r4 geometry: 128-thread blocks (2 waves x 32 q), grid 2048 (32 qt x 64 bh)
// -> 8 blocks/CU, 16 waves/CU (was 2 blocks / 8 waves, grid-limited at 19%
// occupancy). More independent staging streams per CU hide the dedicated
// 2-barrier stage stall under other blocks' compute. The stage semantics
// are UNCHANGED (r2 lesson: the barrier-B stall self-synchronizes the
// same-bh cohort on one XCD -> L2 hits; removing it ballooned FETCH 3.7x).
// Per-wave inner code identical to r3 except one 32-q stream per wave.
// P stays in-register via v_permlane32_swap_b32 (verified r2/r3).
__global__ __launch_bounds__(128, 4)
void fa_mfma(const float* __restrict__ Q, const char* __restrict__ ws,
             float* __restrict__ O) {
    // LDS: K [0,9216) | Vt [9216,18432). Epilogue reuses smem as
    // 2 x 8704B wave-private fp32 scratch.
    __shared__ char smem[18432];
    const int tid = threadIdx.x;
    const int w = tid >> 6, lane = tid & 63;
    const int L5 = lane & 31, h6 = lane >> 5;
    const int h = blockIdx.x & 15, b = (blockIdx.x >> 4) & 3, qt = blockIdx.x >> 6;
    const int bh = b * 16 + h;
    const int q0w = qt * 64 + w * 32;             // wave's q base (32 q per wave)

    const char* Kws  = ws + WS_K;
    const char* Vtws = ws + WS_VT;
    const int qA = q0w + L5;
    const char* mrowA = ws + WS_MB + ((size_t)(b * S + qA)) * 2048 + h6 * 32;

    // ---- Q fragments: direct fp32 global loads + in-reg cvt ----
    short8 qf[4];
#pragma unroll
    for (int ks = 0; ks < 4; ++ks) {
        const float* qp = Q + ((size_t)(b * S + qA)) * E + h * 64 + ks * 16 + h6 * 8;
        float4 a = *(const float4*)qp;
        float4 c = *(const float4*)(qp + 4);
        uint4 u;
        u.x = pk2(a.x, a.y); u.y = pk2(a.z, a.w);
        u.z = pk2(c.x, c.y); u.w = pk2(c.z, c.w);
        qf[ks] = *(short8*)&u;
    }

    f32x16 acc[2];
#pragma unroll
    for (int mb = 0; mb < 2; ++mb) acc[mb] = (f32x16)0.0f;
    float l0 = 0.0f;

    for (int ti = 0; ti < 32; ++ti) {
        // mask bytes for this tile (issued pre-barrier, drained by barrier B)
        const uint4 mAl = *(const uint4*)(mrowA + ti * 64);
        const uint4 mAh = *(const uint4*)(mrowA + ti * 64 + 16);
        const unsigned mdwA[8] = {mAl.x, mAl.y, mAl.z, mAl.w, mAh.x, mAh.y, mAh.z, mAh.w};

        __syncthreads();   // A: previous tile's compute done; buffer free
        {   // stage K tile (9216) + Vt tile (9216): pure linear async copy
            const char* ksrc = Kws + ((size_t)bh * S + ti * 64) * 144;
            const char* vsrc = Vtws + ((size_t)(bh * 32 + ti)) * 9216;
#pragma unroll
            for (int c = 0; c < 9; ++c) {
                int off = (c * 2 + w) * 1024;
                const char* g = (off < 9216) ? (ksrc + off) : (vsrc + off - 9216);
                gl_lds16(g + lane * 16, smem + off);
            }
        }
        __syncthreads();   // B: tiles visible (drains vmcnt)

        const char* bufK = smem;
        const char* bufV = smem + 9216;

        // ---- per 32-key half: QK^T -> softmax -> in-reg P -> partial PV ----
#pragma unroll
        for (int mbK = 0; mbK < 2; ++mbK) {
            short8 kf[4];
#pragma unroll
            for (int ks = 0; ks < 4; ++ks)
                kf[ks] = *(const short8*)(bufK + (mbK * 32 + L5) * 144 + ks * 32 + h6 * 16);

            f32x16 s = (f32x16)0.0f;
            __builtin_amdgcn_s_setprio(1);
#pragma unroll
            for (int ks = 0; ks < 4; ++ks)
                s = __builtin_amdgcn_mfma_f32_32x32x16_bf16(kf[ks], qf[ks], s, 0, 0, 0);
            __builtin_amdgcn_s_setprio(0);

            float lacc = 0.0f;
            unsigned pd[8];
#pragma unroll
            for (int i = 0; i < 8; ++i) {
                float e0 = __builtin_amdgcn_exp2f(s[2 * i]);
                float e1 = __builtin_amdgcn_exp2f(s[2 * i + 1]);
                unsigned pm = pk2(e0, e1);
                const unsigned mv = mdwA[mbK * 4 + (i >> 1)];
                const unsigned am = __builtin_amdgcn_perm(
                    mv, mv, (i & 1) ? 0x03030202u : 0x01010000u);
                pm &= am;                      // masked key -> bf16 +0.0
                pd[i] = pm;
                float lo = __builtin_bit_cast(float, pm << 16);
                float hi = __builtin_bit_cast(float, pm & 0xFFFF0000u);
                lacc += lo + hi;               // l consistent with bf16 P
            }
            l0 += lacc;

            // Lane holds P[k-local] pairs: pd[i] = k {8*(i>>1)+4*h6+2*(i&1)+{0,1}}.
            // Fragment dword t needs keys {s2*16 + h6*8 + 2t,2t+1}; the partner
            // lane (same q, other h6) holds the complementary 4k-blocks.
            // plswap(a,b): a=(a_lo,b_lo), b=(a_hi,b_hi) -> low-reg pack FIRST.
            plswap(pd[0], pd[2]); plswap(pd[1], pd[3]);   // s2=0 slice
            plswap(pd[4], pd[6]); plswap(pd[5], pd[7]);   // s2=1 slice
            uint4 f0; f0.x = pd[0]; f0.y = pd[1]; f0.z = pd[2]; f0.w = pd[3];
            uint4 f1; f1.x = pd[4]; f1.y = pd[5]; f1.z = pd[6]; f1.w = pd[7];
            short8 pf0 = *(short8*)&f0;
            short8 pf1 = *(short8*)&f1;

            // ---- O^T += V^T * P^T for this mbK's 32 keys ----
#pragma unroll
            for (int mbV = 0; mbV < 2; ++mbV) {
                short8 vf0 = *(const short8*)(bufV + (mbV * 32 + L5) * 144
                                              + (mbK * 2 + 0) * 32 + h6 * 16);
                short8 vf1 = *(const short8*)(bufV + (mbV * 32 + L5) * 144
                                              + (mbK * 2 + 1) * 32 + h6 * 16);
                __builtin_amdgcn_s_setprio(1);
                acc[mbV] = __builtin_amdgcn_mfma_f32_32x32x16_bf16(vf0, pf0, acc[mbV], 0, 0, 0);
                acc[mbV] = __builtin_amdgcn_mfma_f32_32x32x16_bf16(vf1, pf1, acc[mbV], 0, 0, 0);
                __builtin_amdgcn_s_setprio(0);
            }
        }
    }

    // ---- epilogue: l-reduce across h6 halves, LDS transpose, store ----
    char* const Pse = smem + w * 8704;
    l0 += __shfl_xor(l0, 32, 64);
    const float inv0 = 1.0f / l0;
    __syncthreads();   // all waves done reading K/V; reuse smem as fp32 scratch
#pragma unroll
    for (int mb = 0; mb < 2; ++mb)
#pragma unroll
        for (int g4 = 0; g4 < 4; ++g4) {
            float4 t;
            t.x = acc[mb][g4 * 4 + 0] * inv0;
            t.y = acc[mb][g4 * 4 + 1] * inv0;
            t.z = acc[mb][g4 * 4 + 2] * inv0;
            t.w = acc[mb][g4 * 4 + 3] * inv0;
            *(float4*)(Pse + (L5 * 68 + mb * 32 + g4 * 8 + h6 * 4) * 4) = t;
        }
    __builtin_amdgcn_s_waitcnt(0xc07f);   // lgkmcnt(0): writes done
    {
        const int r16 = lane >> 4, dc = lane & 15;
#pragma unroll
        for (int i = 0; i < 8; ++i) {
            const int row = i * 4 + r16;
            float4 t = *(const float4*)(Pse + (row * 68 + dc * 4) * 4);
            *(float4*)(O + ((size_t)b * S + q0w + row) * E + h * 64 + dc * 4) = t;
        }
    }
}

// ---------------- fallback (round-1 fp32 kernel, known-correct) ----------------
constexpr int QT = 64, KT = 64, LD = D + 4;
constexpr float SCALE = 0.125f;
__global__ __launch_bounds__(256, 3)
void fa_fp32(const float* __restrict__ Q, const float* __restrict__ K,
             const float* __restrict__ V, const int* __restrict__ M,
             float* __restrict__ Out)
{
    __shared__ float Qs[QT][LD];
    __shared__ float Vs[KT][LD];
    __shared__ float KPs[KT][LD];
    const int tid = threadIdx.x, tx = tid & 15, ty = tid >> 4;
    const int bid = blockIdx.x;
    const int h = bid % H, b = (bid / H) % B, qt = bid / (H * B);
    const int q0 = qt * QT;
    {
        const int col = tx * 4;
#pragma unroll
        for (int i = 0; i < 4; ++i) {
            const int row = ty + i * 16;
            *(float4*)&Qs[row][col] = *(const float4*)&Q[((size_t)(b * S + q0 + row)) * E + h * D + col];
        }
    }
    const int qr0 = ty * 4, d0 = tx * 4;
    float acc[4][4] = {};
    float m_i[4], l_i[4];
#pragma unroll
    for (int j = 0; j < 4; ++j) { m_i[j] = -INFINITY; l_i[j] = 0.0f; }
    for (int kt = 0; kt < S; kt += KT) {
        __syncthreads();
        {
            const int col = tx * 4;
#pragma unroll
            for (int i = 0; i < 4; ++i) {
                const int row = ty + i * 16;
                const size_t g = ((size_t)(b * S + kt + row)) * E + h * D + col;
                *(float4*)&KPs[row][col] = *(const float4*)&K[g];
                *(float4*)&Vs[row][col] = *(const float4*)&V[g];
            }
        }
        __syncthreads();
        float s[4][4] = {};
#pragma unroll
        for (int d = 0; d < D; d += 4) {
            float4 a[4], bb[4];
#pragma unroll
            for (int j = 0; j < 4; ++j) a[j] = *(const float4*)&Qs[qr0 + j][d];
#pragma unroll
            for (int i = 0; i < 4; ++i) bb[i] = *(const float4*)&KPs[tx + 16 * i][d];
#pragma unroll
            for (int j = 0; j < 4; ++j)
#pragma unroll
                for (int i = 0; i < 4; ++i)
                    s[j][i] += a[j].x * bb[i].x + a[j].y * bb[i].y + a[j].z * bb[i].z + a[j].w * bb[i].w;
        }
#pragma unroll
        for (int j = 0; j < 4; ++j) {
            const int* mrow = &M[((size_t)b * S + (q0 + qr0 + j)) * S + kt];
#pragma unroll
            for (int i = 0; i < 4; ++i) {
                const int mk = mrow[tx + 16 * i];
                s[j][i] = mk ? s[j][i] * SCALE : NEGF;
            }
        }
#pragma unroll
        for (int j = 0; j < 4; ++j) {
            float tm = fmaxf(fmaxf(s[j][0], s[j][1]), fmaxf(s[j][2], s[j][3]));
#pragma unroll
            for (int off = 8; off; off >>= 1) tm = fmaxf(tm, __shfl_xor(tm, off, 16));
            const float nm = fmaxf(m_i[j], tm);
            const float alpha = __expf(m_i[j] - nm);
            m_i[j] = nm;
            float rs = 0.0f;
#pragma unroll
            for (int i = 0; i < 4; ++i) { const float p = __expf(s[j][i] - nm); s[j][i] = p; rs += p; }
#pragma unroll
            for (int off = 8; off; off >>= 1) rs += __shfl_xor(rs, off, 16);
            l_i[j] = l_i[j] * alpha + rs;
#pragma unroll
            for (int dd = 0; dd < 4; ++dd) acc[j][dd] *= alpha;
        }
        __syncthreads();
#pragma unroll
        for (int j = 0; j < 4; ++j)
#pragma unroll
            for (int i = 0; i < 4; ++i) KPs[qr0 + j][tx + 16 * i] = s[j][i];
        __syncthreads();
#pragma unroll 4
        for (int kk = 0; kk < KT; kk += 4) {
            float4 p[4], vv[4];
#pragma unroll
            for (int j = 0; j < 4; ++j) p[j] = *(const float4*)&KPs[qr0 + j][kk];
#pragma unroll
            for (int u = 0; u < 4; ++u) vv[u] = *(const float4*)&Vs[kk + u][d0];
#pragma unroll
            for (int j = 0; j < 4; ++j) {
                acc[j][0] += p[j].x * vv[0].x + p[j].y * vv[1].x + p[j].z * vv[2].x + p[j].w * vv[3].x;
                acc[j][1] += p[j].x * vv[0].y + p[j].y * vv[1].y + p[j].z * vv[2].y + p[j].w * vv[3].y;
                acc[j][2] += p[j].x * vv[0].z + p[j].y * vv[1].z + p[j].z * vv[2].z + p[j].w * vv[3].z;
                acc[j][3] += p[j].x * vv[0].w + p[j].y * vv[1].w + p[j].z * vv[2].w + p[j].w * vv[3].w;
            }
        }
    }
#pragma unroll
    for (int j = 0; j < 4; ++j) {
        const float iv = 1.0f / l_i[j];
        float4 r;
        r.x = acc[j][0] * iv; r.y = acc[j][1] * iv; r.z = acc[j][2] * iv; r.w = acc[j][3] * iv;
        *(float4*)&Out[((size_t)(b * S + q0 + qr0 + j)) * E + h * D + d0] = r;
    }
}

extern "C" void kernel_launch(void* const* d_in, const int* in_sizes, int n_in,
                              void* d_out, int out_size, void* d_ws, size_t ws_size,
                              hipStream_t stream) {
    (void)in_sizes; (void)n_in; (void)out_size;
    const float* q = (const float*)d_in[0];
    const float* k = (const float*)d_in[1];
    const float* v = (const float*)d_in[2];
    const int*   m = (const int*)d_in[3];
    float* out = (float*)d_out;

    if (ws_size >= WS_NEED) {
        char* ws = (char*)d_ws;
        prep_all<<<2048, 256, 0, stream>>>(k, v, m, ws);
        fa_mfma<<<2048, 128, 0, stream>>>(q, ws, out);
    } else {
        fa_fp32<<<B * H * (S / QT), 256, 0, stream>>>(q, k, v, m, out);
    }
}

// Round 6
// 290.317 us; speedup vs baseline: 1.0362x; 1.0362x over previous
//
#include <hip/hip_runtime.h>
#include <hip/hip_bf16.h>
#include <math.h>

// Problem constants (match reference)
constexpr int B = 4, S = 2048, E = 1024, H = 16, D = 64;
constexpr float NEGF = -1000000000.0f;
// scale folded into K pre-pass: 1/sqrt(64) * log2(e)  -> softmax uses exp2
constexpr float KSCALE = 0.125f * 1.44269504f;

typedef __attribute__((ext_vector_type(8))) short short8;   // 8 bf16 = 4 VGPRs
typedef __attribute__((ext_vector_type(16))) float f32x16;  // MFMA 32x32 C/D

// ---------------- helpers ----------------
// fast bf16 pair pack, round-half-up: 2 adds + 1 v_perm (vs ~14-instr RNE)
__device__ inline unsigned pk2(float a, float b) {
    unsigned ua = __builtin_bit_cast(unsigned, a) + 0x8000u;
    unsigned ub = __builtin_bit_cast(unsigned, b) + 0x8000u;
    return __builtin_amdgcn_perm(ub, ua, 0x07060302u);
}
__device__ inline void gl_lds16(const void* g, void* l) {
    __builtin_amdgcn_global_load_lds(
        (const __attribute__((address_space(1))) unsigned int*)g,
        (__attribute__((address_space(3))) unsigned int*)l, 16, 0, 0);
}
// v_permlane32_swap_b32 vdst, vsrc: exchanges vdst's UPPER 32 lanes with
// vsrc's LOWER 32 lanes. After plswap(a,b):
//   lanes 0-31:  a = old a[l]      , b = old a[l+32]
//   lanes 32-63: a = old b[l-32]   , b = old b[l]
// i.e. a = (a_lo, b_lo), b = (a_hi, b_hi) by half-content. (Verified r2.)
__device__ inline void plswap(unsigned& a, unsigned& b) {
    asm volatile("v_permlane32_swap_b32 %0, %1" : "+v"(a), "+v"(b));
}

// ws layout (bytes):
//   Kws  [bh][s][72 bf16]          @ 0          18,874,368   (bf16, *KSCALE)
//   Vtws [bh][kt][64 d][72 bf16]   @ 18874368   18,874,368   (per-tile chunked)
//   Mby  [b][q][tile][64 bytes]    @ 37748736   16,777,216   (0x00/0xFF, permuted)
constexpr size_t WS_K  = 0;
constexpr size_t WS_VT = 18874368;
constexpr size_t WS_MB = 37748736;
constexpr size_t WS_NEED = 54525952;

// ---------------- fused pre-pass: K-cvt, V-transpose, mask-bytes ------------
__global__ void prep_all(const float* __restrict__ K, const float* __restrict__ V,
                         const int* __restrict__ M, char* __restrict__ ws) {
    __shared__ float Vf[64][69];
    const int bid = blockIdx.x, tid = threadIdx.x;

    // ---- K convert: dst row = (b*H+h)*S + s, 72 bf16/row ----
    {
        int g = bid * 256 + tid;
        int rowd = g >> 2, qtr = g & 3;
        int b = rowd >> 15, h = (rowd >> 11) & 15, s = rowd & 2047;
        const float* p = K + ((size_t)(b * S + s)) * E + h * 64 + qtr * 16;
        float4 v0 = *(const float4*)(p + 0),  v1 = *(const float4*)(p + 4);
        float4 v2 = *(const float4*)(p + 8),  v3 = *(const float4*)(p + 12);
        uint4 o0, o1;
        o0.x = pk2(v0.x * KSCALE, v0.y * KSCALE); o0.y = pk2(v0.z * KSCALE, v0.w * KSCALE);
        o0.z = pk2(v1.x * KSCALE, v1.y * KSCALE); o0.w = pk2(v1.z * KSCALE, v1.w * KSCALE);
        o1.x = pk2(v2.x * KSCALE, v2.y * KSCALE); o1.y = pk2(v2.z * KSCALE, v2.w * KSCALE);
        o1.z = pk2(v3.x * KSCALE, v3.y * KSCALE); o1.w = pk2(v3.z * KSCALE, v3.w * KSCALE);
        char* d = ws + WS_K + (size_t)rowd * 144 + qtr * 32;
        *(uint4*)d = o0; *(uint4*)(d + 16) = o1;
        if (qtr == 3) {
            uint4 z; z.x = z.y = z.z = z.w = 0;
            *(uint4*)(d + 32) = z;
        }
    }

    // ---- V transpose: tile (bh,kt) -> 64 d-rows x 72 bf16 ----
    {
        int bh = bid >> 5, kt = bid & 31;
        int b = bh >> 4, h = bh & 15;
        {
            int r = tid >> 2, c4 = (tid & 3) * 16;
            const float* p = V + ((size_t)(b * S + kt * 64 + r)) * E + h * 64 + c4;
            float4 a = *(const float4*)(p + 0), bb = *(const float4*)(p + 4);
            float4 c = *(const float4*)(p + 8), dd = *(const float4*)(p + 12);
            *(float4*)&Vf[r][c4 + 0] = a;  *(float4*)&Vf[r][c4 + 4] = bb;
            *(float4*)&Vf[r][c4 + 8] = c;  *(float4*)&Vf[r][c4 + 12] = dd;
        }
        __syncthreads();
        int d = tid >> 2, sq = (tid & 3) * 16;
        float v[16];
#pragma unroll
        for (int i = 0; i < 16; ++i) v[i] = Vf[sq + i][d];
        uint4 o0, o1;
        o0.x = pk2(v[0], v[1]);   o0.y = pk2(v[2], v[3]);
        o0.z = pk2(v[4], v[5]);   o0.w = pk2(v[6], v[7]);
        o1.x = pk2(v[8], v[9]);   o1.y = pk2(v[10], v[11]);
        o1.z = pk2(v[12], v[13]); o1.w = pk2(v[14], v[15]);
        char* o = ws + WS_VT + ((size_t)(bh * 32 + kt)) * 9216 + d * 144 + sq * 2;
        *(uint4*)o = o0; *(uint4*)(o + 16) = o1;
        if (sq == 48) {
            uint4 z; z.x = z.y = z.z = z.w = 0;
            *(uint4*)(o + 32) = z;
        }
    }

    // ---- mask -> permuted byte-mask (0x00/0xFF per key) ----
    {
        unsigned* Mb = (unsigned*)(ws + WS_MB);
        const int t = bid * 256 + tid;
#pragma unroll
        for (int it = 0; it < 8; ++it) {
            int gidx = it * 524288 + t;
            int4 mv = *((const int4*)M + gidx);
            unsigned d = (mv.x ? 0xFFu : 0u) | (mv.y ? 0xFF00u : 0u)
                       | (mv.z ? 0xFF0000u : 0u) | (mv.w ? 0xFF000000u : 0u);
            int row = gidx >> 4, g = gidx & 15;
            Mb[row * 16 + (g & 1) * 8 + (g >> 1)] = d;
        }
    }
}

// ---------------- main: split K/V stage, vmcnt(0)-only waits ----------------
// r6: r3 geometry (256 thr = 4 waves, 64 q/wave, grid 512) with the stage
// drain split into two all-the-way waits (NO counted vmcnt — r5's counted
// vmcnt over a mixed queue of VGPR-return mask loads + LDS-DMA gl_lds is
// the prime suspect for its corruption; retirement order across the two
// return paths is unverified):
//   maskloads | s_barrier(A) | issue K | vmcnt(0) -> K+masks landed |
//   s_barrier(B1) | issue V | QK^T + softmax (V in flight ~1100cyc) |
//   vmcnt(0) | s_barrier(B2) | PV.
// V transfer+latency hides under QK/softmax; mask drain folds into K wait.
// Cohort pacing preserved (r2 lesson): every block fully waits for tile-i
// K and V INSIDE tile i — no tile-ahead buffering.
// P stays in-register via v_permlane32_swap_b32 (verified r2/r3); pk2
// pack (verified) — compute path bit-identical to r3.
__global__ __launch_bounds__(256, 2)
void fa_mfma(const float* __restrict__ Q, const char* __restrict__ ws,
             float* __restrict__ O) {
    // LDS: K [0,9216) | Vt [9216,18432). Epilogue reuses smem as
    // 4 x 8704B wave-private fp32 scratch (34816 B total).
    __shared__ char smem[34816];
    const int tid = threadIdx.x;
    const int w = tid >> 6, lane = tid & 63;
    const int L5 = lane & 31, h6 = lane >> 5;
    const int h = blockIdx.x & 15, b = (blockIdx.x >> 4) & 3, qt = blockIdx.x >> 6;
    const int bh = b * 16 + h;
    const int q0w = qt * 256 + w * 64;            // wave's q base

    const char* Kws  = ws + WS_K;
    const char* Vtws = ws + WS_VT;
    const int qA = q0w + L5, qB = qA + 32;
    const char* mrowA = ws + WS_MB + ((size_t)(b * S + qA)) * 2048 + h6 * 32;
    const char* mrowB = ws + WS_MB + ((size_t)(b * S + qB)) * 2048 + h6 * 32;

    // ---- Q fragments: direct fp32 global loads + in-reg cvt ----
    short8 qf[2][4];
#pragma unroll
    for (int nb = 0; nb < 2; ++nb)
#pragma unroll
        for (int ks = 0; ks < 4; ++ks) {
            const float* qp = Q + ((size_t)(b * S + q0w + nb * 32 + L5)) * E
                                + h * 64 + ks * 16 + h6 * 8;
            float4 a = *(const float4*)qp;
            float4 c = *(const float4*)(qp + 4);
            uint4 u;
            u.x = pk2(a.x, a.y); u.y = pk2(a.z, a.w);
            u.z = pk2(c.x, c.y); u.w = pk2(c.z, c.w);
            qf[nb][ks] = *(short8*)&u;
        }

    f32x16 acc[2][2];
#pragma unroll
    for (int mb = 0; mb < 2; ++mb)
#pragma unroll
        for (int nb = 0; nb < 2; ++nb) acc[mb][nb] = (f32x16)0.0f;
    float l0 = 0.0f, l1 = 0.0f;

    for (int ti = 0; ti < 32; ++ti) {
        // mask bytes for this tile (issued pre-barrier; drained at K vmcnt(0))
        const uint4 mAl = *(const uint4*)(mrowA + ti * 64);
        const uint4 mAh = *(const uint4*)(mrowA + ti * 64 + 16);
        const uint4 mBl = *(const uint4*)(mrowB + ti * 64);
        const uint4 mBh = *(const uint4*)(mrowB + ti * 64 + 16);
        const unsigned mdwA[8] = {mAl.x, mAl.y, mAl.z, mAl.w, mAh.x, mAh.y, mAh.z, mAh.w};
        const unsigned mdwB[8] = {mBl.x, mBl.y, mBl.z, mBl.w, mBh.x, mBh.y, mBh.z, mBh.w};
        __builtin_amdgcn_sched_barrier(0);

        __builtin_amdgcn_s_barrier();        // A (raw): prev compute done
        __builtin_amdgcn_sched_barrier(0);

        const char* ksrc = Kws + ((size_t)bh * S + ti * 64) * 144;
        const char* vsrc = Vtws + ((size_t)(bh * 32 + ti)) * 9216;

        // ---- issue K chunks (idx 0..8 -> LDS [0,9216)) ----
#pragma unroll
        for (int c = 0; c < 5; ++c) {
            int idx = c * 4 + w;
            if (idx < 9)
                gl_lds16(ksrc + idx * 1024 + lane * 16, smem + idx * 1024);
        }
        __builtin_amdgcn_sched_barrier(0);
        asm volatile("s_waitcnt vmcnt(0)" ::: "memory");   // K + masks landed
        __builtin_amdgcn_sched_barrier(0);
        __builtin_amdgcn_s_barrier();        // B1: K visible to all waves
        __builtin_amdgcn_sched_barrier(0);

        // ---- issue V chunks (idx 9..17 -> LDS [9216,18432)) ----
#pragma unroll
        for (int c = 0; c < 5; ++c) {
            int idx = c * 4 + w;
            if (idx >= 9 && idx < 18)
                gl_lds16(vsrc + (idx - 9) * 1024 + lane * 16, smem + idx * 1024);
        }
        __builtin_amdgcn_sched_barrier(0);   // pin V issue BEFORE QK^T

        const char* bufK = smem;
        const char* bufV = smem + 9216;

        // ---- QK^T -> softmax -> in-reg P (V loads in flight) ----
        short8 pf[2][2][2];   // [mbK][nb][k16-slice]
#pragma unroll
        for (int mbK = 0; mbK < 2; ++mbK) {
            short8 kf[4];
#pragma unroll
            for (int ks = 0; ks < 4; ++ks)
                kf[ks] = *(const short8*)(bufK + (mbK * 32 + L5) * 144 + ks * 32 + h6 * 16);
#pragma unroll
            for (int nb = 0; nb < 2; ++nb) {
                f32x16 s = (f32x16)0.0f;
                __builtin_amdgcn_s_setprio(1);
#pragma unroll
                for (int ks = 0; ks < 4; ++ks)
                    s = __builtin_amdgcn_mfma_f32_32x32x16_bf16(kf[ks], qf[nb][ks], s, 0, 0, 0);
                __builtin_amdgcn_s_setprio(0);

                const unsigned* mdw = nb ? mdwB : mdwA;
                float lacc = 0.0f;
                unsigned pd[8];
#pragma unroll
                for (int i = 0; i < 8; ++i) {
                    float e0 = __builtin_amdgcn_exp2f(s[2 * i]);
                    float e1 = __builtin_amdgcn_exp2f(s[2 * i + 1]);
                    unsigned pm = pk2(e0, e1);
                    const unsigned mv = mdw[mbK * 4 + (i >> 1)];
                    const unsigned am = __builtin_amdgcn_perm(
                        mv, mv, (i & 1) ? 0x03030202u : 0x01010000u);
                    pm &= am;                      // masked key -> bf16 +0.0
                    pd[i] = pm;
                    float lo = __builtin_bit_cast(float, pm << 16);
                    float hi = __builtin_bit_cast(float, pm & 0xFFFF0000u);
                    lacc += lo + hi;               // l consistent with bf16 P
                }
                if (nb) l1 += lacc; else l0 += lacc;

                // Lane holds P[k-local] pairs: pd[i] = k {8*(i>>1)+4*h6+2*(i&1)+{0,1}}.
                // plswap(a,b): a=(a_lo,b_lo), b=(a_hi,b_hi) -> low-reg pack FIRST.
                plswap(pd[0], pd[2]); plswap(pd[1], pd[3]);   // s2=0 slice
                plswap(pd[4], pd[6]); plswap(pd[5], pd[7]);   // s2=1 slice
                uint4 f0; f0.x = pd[0]; f0.y = pd[1]; f0.z = pd[2]; f0.w = pd[3];
                uint4 f1; f1.x = pd[4]; f1.y = pd[5]; f1.z = pd[6]; f1.w = pd[7];
                pf[mbK][nb][0] = *(short8*)&f0;
                pf[mbK][nb][1] = *(short8*)&f1;
            }
        }

        // ---- V wait + barrier, then PV ----
        __builtin_amdgcn_sched_barrier(0);
        asm volatile("s_waitcnt vmcnt(0)" ::: "memory");
        __builtin_amdgcn_sched_barrier(0);
        __builtin_amdgcn_s_barrier();        // B2: V visible
        __builtin_amdgcn_sched_barrier(0);

        // ---- O^T += V^T * P^T (same accumulation order as r3) ----
#pragma unroll
        for (int mbK = 0; mbK < 2; ++mbK)
#pragma unroll
            for (int mbV = 0; mbV < 2; ++mbV) {
                short8 vf0 = *(const short8*)(bufV + (mbV * 32 + L5) * 144
                                              + (mbK * 2 + 0) * 32 + h6 * 16);
                short8 vf1 = *(const short8*)(bufV + (mbV * 32 + L5) * 144
                                              + (mbK * 2 + 1) * 32 + h6 * 16);
                __builtin_amdgcn_s_setprio(1);
#pragma unroll
                for (int nb = 0; nb < 2; ++nb) {
                    acc[mbV][nb] = __builtin_amdgcn_mfma_f32_32x32x16_bf16(
                        vf0, pf[mbK][nb][0], acc[mbV][nb], 0, 0, 0);
                    acc[mbV][nb] = __builtin_amdgcn_mfma_f32_32x32x16_bf16(
                        vf1, pf[mbK][nb][1], acc[mbV][nb], 0, 0, 0);
                }
                __builtin_amdgcn_s_setprio(0);
            }
    }

    // ---- epilogue: l-reduce across h6 halves, LDS transpose, store ----
    char* const Pse = smem + w * 8704;
    l0 += __shfl_xor(l0, 32, 64);
    l1 += __shfl_xor(l1, 32, 64);
    const float inv[2] = {1.0f / l0, 1.0f / l1};
    __syncthreads();   // full drain; reuse smem as fp32 scratch
#pragma unroll
    for (int nb = 0; nb < 2; ++nb) {
#pragma unroll
        for (int mb = 0; mb < 2; ++mb)
#pragma unroll
            for (int g4 = 0; g4 < 4; ++g4) {
                float4 t;
                t.x = acc[mb][nb][g4 * 4 + 0] * inv[nb];
                t.y = acc[mb][nb][g4 * 4 + 1] * inv[nb];
                t.z = acc[mb][nb][g4 * 4 + 2] * inv[nb];
                t.w = acc[mb][nb][g4 * 4 + 3] * inv[nb];
                *(float4*)(Pse + (L5 * 68 + mb * 32 + g4 * 8 + h6 * 4) * 4) = t;
            }
        __builtin_amdgcn_s_waitcnt(0xc07f);   // lgkmcnt(0): writes done
        const int r16 = lane >> 4, dc = lane & 15;
#pragma unroll
        for (int i = 0; i < 8; ++i) {
            const int row = i * 4 + r16;
            float4 t = *(const float4*)(Pse + (row * 68 + dc * 4) * 4);
            *(float4*)(O + ((size_t)b * S + q0w + nb * 32 + row) * E + h * 64 + dc * 4) = t;
        }
        __builtin_amdgcn_s_waitcnt(0xc07f);   // reads done before nb=1 overwrites
    }
}

// ---------------- fallback (round-1 fp32 kernel, known-correct) ----------------
constexpr int QT = 64, KT = 64, LD = D + 4;
constexpr float SCALE = 0.125f;
__global__ __launch_bounds__(256, 3)
void fa_fp32(const float* __restrict__ Q, const float* __restrict__ K,
             const float* __restrict__ V, const int* __restrict__ M,
             float* __restrict__ Out)
{
    __shared__ float Qs[QT][LD];
    __shared__ float Vs[KT][LD];
    __shared__ float KPs[KT][LD];
    const int tid = threadIdx.x, tx = tid & 15, ty = tid >> 4;
    const int bid = blockIdx.x;
    const int h = bid % H, b = (bid / H) % B, qt = bid / (H * B);
    const int q0 = qt * QT;
    {
        const int col = tx * 4;
#pragma unroll
        for (int i = 0; i < 4; ++i) {
            const int row = ty + i * 16;
            *(float4*)&Qs[row][col] = *(const float4*)&Q[((size_t)(b * S + q0 + row)) * E + h * D + col];
        }
    }
    const int qr0 = ty * 4, d0 = tx * 4;
    float acc[4][4] = {};
    float m_i[4], l_i[4];
#pragma unroll
    for (int j = 0; j < 4; ++j) { m_i[j] = -INFINITY; l_i[j] = 0.0f; }
    for (int kt = 0; kt < S; kt += KT) {
        __syncthreads();
        {
            const int col = tx * 4;
#pragma unroll
            for (int i = 0; i < 4; ++i) {
                const int row = ty + i * 16;
                const size_t g = ((size_t)(b * S + kt + row)) * E + h * D + col;
                *(float4*)&KPs[row][col] = *(const float4*)&K[g];
                *(float4*)&Vs[row][col] = *(const float4*)&V[g];
            }
        }
        __syncthreads();
        float s[4][4] = {};
#pragma unroll
        for (int d = 0; d < D; d += 4) {
            float4 a[4], bb[4];
#pragma unroll
            for (int j = 0; j < 4; ++j) a[j] = *(const float4*)&Qs[qr0 + j][d];
#pragma unroll
            for (int i = 0; i < 4; ++i) bb[i] = *(const float4*)&KPs[tx + 16 * i][d];
#pragma unroll
            for (int j = 0; j < 4; ++j)
#pragma unroll
                for (int i = 0; i < 4; ++i)
                    s[j][i] += a[j].x * bb[i].x + a[j].y * bb[i].y + a[j].z * bb[i].z + a[j].w * bb[i].w;
        }
#pragma unroll
        for (int j = 0; j < 4; ++j) {
            const int* mrow = &M[((size_t)b * S + (q0 + qr0 + j)) * S + kt];
#pragma unroll
            for (int i = 0; i < 4; ++i) {
                const int mk = mrow[tx + 16 * i];
                s[j][i] = mk ? s[j][i] * SCALE : NEGF;
            }
        }
#pragma unroll
        for (int j = 0; j < 4; ++j) {
            float tm = fmaxf(fmaxf(s[j][0], s[j][1]), fmaxf(s[j][2], s[j][3]));
#pragma unroll
            for (int off = 8; off; off >>= 1) tm = fmaxf(tm, __shfl_xor(tm, off, 16));
            const float nm = fmaxf(m_i[j], tm);
            const float alpha = __expf(m_i[j] - nm);
            m_i[j] = nm;
            float rs = 0.0f;
#pragma unroll
            for (int i = 0; i < 4; ++i) { const float p = __expf(s[j][i] - nm); s[j][i] = p; rs += p; }
#pragma unroll
            for (int off = 8; off; off >>= 1) rs += __shfl_xor(rs, off, 16);
            l_i[j] = l_i[j] * alpha + rs;
#pragma unroll
            for (int dd = 0; dd < 4; ++dd) acc[j][dd] *= alpha;
        }
        __syncthreads();
#pragma unroll
        for (int j = 0; j < 4; ++j)
#pragma unroll
            for (int i = 0; i < 4; ++i) KPs[qr0 + j][tx + 16 * i] = s[j][i];
        __syncthreads();
#pragma unroll 4
        for (int kk = 0; kk < KT; kk += 4) {
            float4 p[4], vv[4];
#pragma unroll
            for (int j = 0; j < 4; ++j) p[j] = *(const float4*)&KPs[qr0 + j][kk];
#pragma unroll
            for (int u = 0; u < 4; ++u) vv[u] = *(const float4*)&Vs[kk + u][d0];
#pragma unroll
            for (int j = 0; j < 4; ++j) {
                acc[j][0] += p[j].x * vv[0].x + p[j].y * vv[1].x + p[j].z * vv[2].x + p[j].w * vv[3].x;
                acc[j][1] += p[j].x * vv[0].y + p[j].y * vv[1].y + p[j].z * vv[2].y + p[j].w * vv[3].y;
                acc[j][2] += p[j].x * vv[0].z + p[j].y * vv[1].z + p[j].z * vv[2].z + p[j].w * vv[3].z;
                acc[j][3] += p[j].x * vv[0].w + p[j].y * vv[1].w + p[j].z * vv[2].w + p[j].w * vv[3].w;
            }
        }
    }
#pragma unroll
    for (int j = 0; j < 4; ++j) {
        const float iv = 1.0f / l_i[j];
        float4 r;
        r.x = acc[j][0] * iv; r.y = acc[j][1] * iv; r.z = acc[j][2] * iv; r.w = acc[j][3] * iv;
        *(float4*)&Out[((size_t)(b * S + q0 + qr0 + j)) * E + h * D + d0] = r;
    }
}

extern "C" void kernel_launch(void* const* d_in, const int* in_sizes, int n_in,
                              void* d_out, int out_size, void* d_ws, size_t ws_size,
                              hipStream_t stream) {
    (void)in_sizes; (void)n_in; (void)out_size;
    const float* q = (const float*)d_in[0];
    const float* k = (const float*)d_in[1];
    const float* v = (const float*)d_in[2];
    const int*   m = (const int*)d_in[3];
    float* out = (float*)d_out;

    if (ws_size >= WS_NEED) {
        char* ws = (char*)d_ws;
        prep_all<<<2048, 256, 0, stream>>>(k, v, m, ws);
        fa_mfma<<<512, 256, 0, stream>>>(q, ws, out);
    } else {
        fa_fp32<<<B * H * (S / QT), 256, 0, stream>>>(q, k, v, m, out);
    }
}

// Round 9
// 280.695 us; speedup vs baseline: 1.0718x; 1.0343x over previous
//
#include <hip/hip_runtime.h>
#include <hip/hip_bf16.h>
#include <math.h>

// Problem constants (match reference)
constexpr int B = 4, S = 2048, E = 1024, H = 16, D = 64;
constexpr float NEGF = -1000000000.0f;
// scale folded into K pre-pass: 1/sqrt(64) * log2(e)  -> softmax uses exp2
constexpr float KSCALE = 0.125f * 1.44269504f;

typedef __attribute__((ext_vector_type(8))) short short8;   // 8 bf16 = 4 VGPRs
typedef __attribute__((ext_vector_type(16))) float f32x16;  // MFMA 32x32 C/D

// ---------------- helpers ----------------
// fast bf16 pair pack, round-half-up: 2 adds + 1 v_perm (vs ~14-instr RNE)
__device__ inline unsigned pk2(float a, float b) {
    unsigned ua = __builtin_bit_cast(unsigned, a) + 0x8000u;
    unsigned ub = __builtin_bit_cast(unsigned, b) + 0x8000u;
    return __builtin_amdgcn_perm(ub, ua, 0x07060302u);
}
__device__ inline void gl_lds16(const void* g, void* l) {
    __builtin_amdgcn_global_load_lds(
        (const __attribute__((address_space(1))) unsigned int*)g,
        (__attribute__((address_space(3))) unsigned int*)l, 16, 0, 0);
}
// v_permlane32_swap_b32 vdst, vsrc: exchanges vdst's UPPER 32 lanes with
// vsrc's LOWER 32 lanes. After plswap(a,b):
//   lanes 0-31:  a = old a[l]      , b = old a[l+32]
//   lanes 32-63: a = old b[l-32]   , b = old b[l]
// i.e. a = (a_lo, b_lo), b = (a_hi, b_hi) by half-content. (Verified r2.)
__device__ inline void plswap(unsigned& a, unsigned& b) {
    asm volatile("v_permlane32_swap_b32 %0, %1" : "+v"(a), "+v"(b));
}

// ws layout (bytes):
//   Kws  [bh][s][72 bf16]          @ 0          18,874,368   (bf16, *KSCALE)
//   Vtws [bh][kt][64 d][72 bf16]   @ 18874368   18,874,368   (per-tile chunked)
//   Mby  [b][q][tile][64 bytes]    @ 37748736   16,777,216   (0x00/0xFF, permuted)
constexpr size_t WS_K  = 0;
constexpr size_t WS_VT = 18874368;
constexpr size_t WS_MB = 37748736;
constexpr size_t WS_NEED = 54525952;

// ---------------- fused pre-pass: K-cvt, V-transpose, mask-bytes ------------
__global__ void prep_all(const float* __restrict__ K, const float* __restrict__ V,
                         const int* __restrict__ M, char* __restrict__ ws) {
    __shared__ float Vf[64][69];
    const int bid = blockIdx.x, tid = threadIdx.x;

    // ---- K convert: dst row = (b*H+h)*S + s, 72 bf16/row ----
    {
        int g = bid * 256 + tid;
        int rowd = g >> 2, qtr = g & 3;
        int b = rowd >> 15, h = (rowd >> 11) & 15, s = rowd & 2047;
        const float* p = K + ((size_t)(b * S + s)) * E + h * 64 + qtr * 16;
        float4 v0 = *(const float4*)(p + 0),  v1 = *(const float4*)(p + 4);
        float4 v2 = *(const float4*)(p + 8),  v3 = *(const float4*)(p + 12);
        uint4 o0, o1;
        o0.x = pk2(v0.x * KSCALE, v0.y * KSCALE); o0.y = pk2(v0.z * KSCALE, v0.w * KSCALE);
        o0.z = pk2(v1.x * KSCALE, v1.y * KSCALE); o0.w = pk2(v1.z * KSCALE, v1.w * KSCALE);
        o1.x = pk2(v2.x * KSCALE, v2.y * KSCALE); o1.y = pk2(v2.z * KSCALE, v2.w * KSCALE);
        o1.z = pk2(v3.x * KSCALE, v3.y * KSCALE); o1.w = pk2(v3.z * KSCALE, v3.w * KSCALE);
        char* d = ws + WS_K + (size_t)rowd * 144 + qtr * 32;
        *(uint4*)d = o0; *(uint4*)(d + 16) = o1;
        if (qtr == 3) {
            uint4 z; z.x = z.y = z.z = z.w = 0;
            *(uint4*)(d + 32) = z;
        }
    }

    // ---- V transpose: tile (bh,kt) -> 64 d-rows x 72 bf16 ----
    {
        int bh = bid >> 5, kt = bid & 31;
        int b = bh >> 4, h = bh & 15;
        {
            int r = tid >> 2, c4 = (tid & 3) * 16;
            const float* p = V + ((size_t)(b * S + kt * 64 + r)) * E + h * 64 + c4;
            float4 a = *(const float4*)(p + 0), bb = *(const float4*)(p + 4);
            float4 c = *(const float4*)(p + 8), dd = *(const float4*)(p + 12);
            *(float4*)&Vf[r][c4 + 0] = a;  *(float4*)&Vf[r][c4 + 4] = bb;
            *(float4*)&Vf[r][c4 + 8] = c;  *(float4*)&Vf[r][c4 + 12] = dd;
        }
        __syncthreads();
        int d = tid >> 2, sq = (tid & 3) * 16;
        float v[16];
#pragma unroll
        for (int i = 0; i < 16; ++i) v[i] = Vf[sq + i][d];
        uint4 o0, o1;
        o0.x = pk2(v[0], v[1]);   o0.y = pk2(v[2], v[3]);
        o0.z = pk2(v[4], v[5]);   o0.w = pk2(v[6], v[7]);
        o1.x = pk2(v[8], v[9]);   o1.y = pk2(v[10], v[11]);
        o1.z = pk2(v[12], v[13]); o1.w = pk2(v[14], v[15]);
        char* o = ws + WS_VT + ((size_t)(bh * 32 + kt)) * 9216 + d * 144 + sq * 2;
        *(uint4*)o = o0; *(uint4*)(o + 16) = o1;
        if (sq == 48) {
            uint4 z; z.x = z.y = z.z = z.w = 0;
            *(uint4*)(o + 32) = z;
        }
    }

    // ---- mask -> permuted byte-mask (0x00/0xFF per key) ----
    {
        unsigned* Mb = (unsigned*)(ws + WS_MB);
        const int t = bid * 256 + tid;
#pragma unroll
        for (int it = 0; it < 8; ++it) {
            int gidx = it * 524288 + t;
            int4 mv = *((const int4*)M + gidx);
            unsigned d = (mv.x ? 0xFFu : 0u) | (mv.y ? 0xFF00u : 0u)
                       | (mv.z ? 0xFF0000u : 0u) | (mv.w ? 0xFF000000u : 0u);
            int row = gidx >> 4, g = gidx & 15;
            Mb[row * 16 + (g & 1) * 8 + (g >> 1)] = d;
        }
    }
}

// ---------------- main: nb-split 8-wave blocks (no combine) ----------------
// r9: grid 512 (r3 geometry, cohort pacing intact), 512-thread blocks =
// 8 waves x 32 q. Wave (wq,g) owns q rows qt*256 + wq*64 + g*32 — the
// nb-dimension of r3's waves is split across waves instead of carried as
// ILP. NO cross-wave dataflow anywhere (r5/r8's unexplained failures both
// involved the cross-group combine; this has none): per-wave code is r4's
// verified single-stream body; epilogue is r4's wave-private transpose in
// two rounds (g0 waves then g1 waves) with __syncthreads-separated region
// reuse only. All 8 waves share ONE staged K/V buffer (18 chunks spread
// over 8 waves). Waves/SIMD 2 -> 4 at VGPR ~56 hides the dep-chain stalls
// that dominate the compute phase (r6 accounting: ~75% idle at 2 w/SIMD).
// Per-q arithmetic bit-identical to r3 -> absmax unchanged.
__global__ __launch_bounds__(512, 4)
void fa_mfma(const float* __restrict__ Q, const char* __restrict__ ws,
             float* __restrict__ O) {
    // LDS: stage K [0,9216) | Vt [9216,18432); epilogue 4 x 8704 = 34816.
    __shared__ char smem[34816];
    const int tid = threadIdx.x;
    const int w = tid >> 6, lane = tid & 63;
    const int wq = w & 3, g = w >> 2;
    const int L5 = lane & 31, h6 = lane >> 5;
    const int h = blockIdx.x & 15, b = (blockIdx.x >> 4) & 3, qt = blockIdx.x >> 6;
    const int bh = b * 16 + h;
    const int q0w = qt * 256 + wq * 64 + g * 32;   // wave's 32 q rows

    const char* Kws  = ws + WS_K;
    const char* Vtws = ws + WS_VT;
    const int qA = q0w + L5;
    const char* mrowA = ws + WS_MB + ((size_t)(b * S + qA)) * 2048 + h6 * 32;

    // ---- Q fragments: direct fp32 global loads + in-reg cvt ----
    short8 qf[4];
#pragma unroll
    for (int ks = 0; ks < 4; ++ks) {
        const float* qp = Q + ((size_t)(b * S + qA)) * E + h * 64 + ks * 16 + h6 * 8;
        float4 a = *(const float4*)qp;
        float4 c = *(const float4*)(qp + 4);
        uint4 u;
        u.x = pk2(a.x, a.y); u.y = pk2(a.z, a.w);
        u.z = pk2(c.x, c.y); u.w = pk2(c.z, c.w);
        qf[ks] = *(short8*)&u;
    }

    f32x16 acc[2];
#pragma unroll
    for (int mb = 0; mb < 2; ++mb) acc[mb] = (f32x16)0.0f;
    float l0 = 0.0f;

    for (int ti = 0; ti < 32; ++ti) {
        // mask bytes for this tile (issued pre-barrier, drained by barrier B)
        const uint4 mAl = *(const uint4*)(mrowA + ti * 64);
        const uint4 mAh = *(const uint4*)(mrowA + ti * 64 + 16);
        const unsigned mdwA[8] = {mAl.x, mAl.y, mAl.z, mAl.w, mAh.x, mAh.y, mAh.z, mAh.w};

        __syncthreads();   // A: previous tile's compute done; buffer free
        {   // stage K tile (9216) + Vt tile (9216): 18 chunks over 8 waves
            const char* ksrc = Kws + ((size_t)bh * S + ti * 64) * 144;
            const char* vsrc = Vtws + ((size_t)(bh * 32 + ti)) * 9216;
#pragma unroll
            for (int c = 0; c < 3; ++c) {
                int idx = c * 8 + w;
                if (idx < 18) {
                    int off = idx * 1024;
                    const char* gp = (off < 9216) ? (ksrc + off) : (vsrc + off - 9216);
                    gl_lds16(gp + lane * 16, smem + off);
                }
            }
        }
        __syncthreads();   // B: tiles visible (drains vmcnt)

        const char* bufK = smem;
        const char* bufV = smem + 9216;

        // ---- per 32-key half: QK^T -> softmax -> in-reg P -> partial PV ----
#pragma unroll
        for (int mbK = 0; mbK < 2; ++mbK) {
            short8 kf[4];
#pragma unroll
            for (int ks = 0; ks < 4; ++ks)
                kf[ks] = *(const short8*)(bufK + (mbK * 32 + L5) * 144 + ks * 32 + h6 * 16);

            f32x16 s = (f32x16)0.0f;
            __builtin_amdgcn_s_setprio(1);
#pragma unroll
            for (int ks = 0; ks < 4; ++ks)
                s = __builtin_amdgcn_mfma_f32_32x32x16_bf16(kf[ks], qf[ks], s, 0, 0, 0);
            __builtin_amdgcn_s_setprio(0);

            float lacc = 0.0f;
            unsigned pd[8];
#pragma unroll
            for (int i = 0; i < 8; ++i) {
                float e0 = __builtin_amdgcn_exp2f(s[2 * i]);
                float e1 = __builtin_amdgcn_exp2f(s[2 * i + 1]);
                unsigned pm = pk2(e0, e1);
                const unsigned mv = mdwA[mbK * 4 + (i >> 1)];
                const unsigned am = __builtin_amdgcn_perm(
                    mv, mv, (i & 1) ? 0x03030202u : 0x01010000u);
                pm &= am;                      // masked key -> bf16 +0.0
                pd[i] = pm;
                float lo = __builtin_bit_cast(float, pm << 16);
                float hi = __builtin_bit_cast(float, pm & 0xFFFF0000u);
                lacc += lo + hi;               // l consistent with bf16 P
            }
            l0 += lacc;

            // Lane holds P[k-local] pairs: pd[i] = k {8*(i>>1)+4*h6+2*(i&1)+{0,1}}.
            // plswap(a,b): a=(a_lo,b_lo), b=(a_hi,b_hi) -> low-reg pack FIRST.
            plswap(pd[0], pd[2]); plswap(pd[1], pd[3]);   // s2=0 slice
            plswap(pd[4], pd[6]); plswap(pd[5], pd[7]);   // s2=1 slice
            uint4 f0; f0.x = pd[0]; f0.y = pd[1]; f0.z = pd[2]; f0.w = pd[3];
            uint4 f1; f1.x = pd[4]; f1.y = pd[5]; f1.z = pd[6]; f1.w = pd[7];
            short8 pf0 = *(short8*)&f0;
            short8 pf1 = *(short8*)&f1;

            // ---- O^T += V^T * P^T for this mbK's 32 keys ----
#pragma unroll
            for (int mbV = 0; mbV < 2; ++mbV) {
                short8 vf0 = *(const short8*)(bufV + (mbV * 32 + L5) * 144
                                              + (mbK * 2 + 0) * 32 + h6 * 16);
                short8 vf1 = *(const short8*)(bufV + (mbV * 32 + L5) * 144
                                              + (mbK * 2 + 1) * 32 + h6 * 16);
                __builtin_amdgcn_s_setprio(1);
                acc[mbV] = __builtin_amdgcn_mfma_f32_32x32x16_bf16(vf0, pf0, acc[mbV], 0, 0, 0);
                acc[mbV] = __builtin_amdgcn_mfma_f32_32x32x16_bf16(vf1, pf1, acc[mbV], 0, 0, 0);
                __builtin_amdgcn_s_setprio(0);
            }
        }
    }

    // ---- epilogue: l-reduce, wave-private LDS transpose, store ----
    // Two rounds share the 4 x 8704 scratch: g0 waves first, then g1.
    // Each wave writes and reads ONLY its own region (no cross-wave data).
    char* const Pse = smem + wq * 8704;
    l0 += __shfl_xor(l0, 32, 64);
    const float inv0 = 1.0f / l0;
    __syncthreads();   // all compute done; stage buffer free for scratch
#pragma unroll
    for (int rnd = 0; rnd < 2; ++rnd) {
        if (g == rnd) {
#pragma unroll
            for (int mb = 0; mb < 2; ++mb)
#pragma unroll
                for (int g4 = 0; g4 < 4; ++g4) {
                    float4 t;
                    t.x = acc[mb][g4 * 4 + 0] * inv0;
                    t.y = acc[mb][g4 * 4 + 1] * inv0;
                    t.z = acc[mb][g4 * 4 + 2] * inv0;
                    t.w = acc[mb][g4 * 4 + 3] * inv0;
                    *(float4*)(Pse + (L5 * 68 + mb * 32 + g4 * 8 + h6 * 4) * 4) = t;
                }
            __builtin_amdgcn_s_waitcnt(0xc07f);   // lgkmcnt(0): writes done
            const int r16 = lane >> 4, dc = lane & 15;
#pragma unroll
            for (int i = 0; i < 8; ++i) {
                const int row = i * 4 + r16;
                float4 t = *(const float4*)(Pse + (row * 68 + dc * 4) * 4);
                *(float4*)(O + ((size_t)b * S + q0w + row) * E + h * 64 + dc * 4) = t;
            }
        }
        __syncthreads();   // round's reads done before next round overwrites
    }
}

// ---------------- fallback (round-1 fp32 kernel, known-correct) ----------------
constexpr int QT = 64, KT = 64, LD = D + 4;
constexpr float SCALE = 0.125f;
__global__ __launch_bounds__(256, 3)
void fa_fp32(const float* __restrict__ Q, const float* __restrict__ K,
             const float* __restrict__ V, const int* __restrict__ M,
             float* __restrict__ Out)
{
    __shared__ float Qs[QT][LD];
    __shared__ float Vs[KT][LD];
    __shared__ float KPs[KT][LD];
    const int tid = threadIdx.x, tx = tid & 15, ty = tid >> 4;
    const int bid = blockIdx.x;
    const int h = bid % H, b = (bid / H) % B, qt = bid / (H * B);
    const int q0 = qt * QT;
    {
        const int col = tx * 4;
#pragma unroll
        for (int i = 0; i < 4; ++i) {
            const int row = ty + i * 16;
            *(float4*)&Qs[row][col] = *(const float4*)&Q[((size_t)(b * S + q0 + row)) * E + h * D + col];
        }
    }
    const int qr0 = ty * 4, d0 = tx * 4;
    float acc[4][4] = {};
    float m_i[4], l_i[4];
#pragma unroll
    for (int j = 0; j < 4; ++j) { m_i[j] = -INFINITY; l_i[j] = 0.0f; }
    for (int kt = 0; kt < S; kt += KT) {
        __syncthreads();
        {
            const int col = tx * 4;
#pragma unroll
            for (int i = 0; i < 4; ++i) {
                const int row = ty + i * 16;
                const size_t g = ((size_t)(b * S + kt + row)) * E + h * D + col;
                *(float4*)&KPs[row][col] = *(const float4*)&K[g];
                *(float4*)&Vs[row][col] = *(const float4*)&V[g];
            }
        }
        __syncthreads();
        float s[4][4] = {};
#pragma unroll
        for (int d = 0; d < D; d += 4) {
            float4 a[4], bb[4];
#pragma unroll
            for (int j = 0; j < 4; ++j) a[j] = *(const float4*)&Qs[qr0 + j][d];
#pragma unroll
            for (int i = 0; i < 4; ++i) bb[i] = *(const float4*)&KPs[tx + 16 * i][d];
#pragma unroll
            for (int j = 0; j < 4; ++j)
#pragma unroll
                for (int i = 0; i < 4; ++i)
                    s[j][i] += a[j].x * bb[i].x + a[j].y * bb[i].y + a[j].z * bb[i].z + a[j].w * bb[i].w;
        }
#pragma unroll
        for (int j = 0; j < 4; ++j) {
            const int* mrow = &M[((size_t)b * S + (q0 + qr0 + j)) * S + kt];
#pragma unroll
            for (int i = 0; i < 4; ++i) {
                const int mk = mrow[tx + 16 * i];
                s[j][i] = mk ? s[j][i] * SCALE : NEGF;
            }
        }
#pragma unroll
        for (int j = 0; j < 4; ++j) {
            float tm = fmaxf(fmaxf(s[j][0], s[j][1]), fmaxf(s[j][2], s[j][3]));
#pragma unroll
            for (int off = 8; off; off >>= 1) tm = fmaxf(tm, __shfl_xor(tm, off, 16));
            const float nm = fmaxf(m_i[j], tm);
            const float alpha = __expf(m_i[j] - nm);
            m_i[j] = nm;
            float rs = 0.0f;
#pragma unroll
            for (int i = 0; i < 4; ++i) { const float p = __expf(s[j][i] - nm); s[j][i] = p; rs += p; }
#pragma unroll
            for (int off = 8; off; off >>= 1) rs += __shfl_xor(rs, off, 16);
            l_i[j] = l_i[j] * alpha + rs;
#pragma unroll
            for (int dd = 0; dd < 4; ++dd) acc[j][dd] *= alpha;
        }
        __syncthreads();
#pragma unroll
        for (int j = 0; j < 4; ++j)
#pragma unroll
            for (int i = 0; i < 4; ++i) KPs[qr0 + j][tx + 16 * i] = s[j][i];
        __syncthreads();
#pragma unroll 4
        for (int kk = 0; kk < KT; kk += 4) {
            float4 p[4], vv[4];
#pragma unroll
            for (int j = 0; j < 4; ++j) p[j] = *(const float4*)&KPs[qr0 + j][kk];
#pragma unroll
            for (int u = 0; u < 4; ++u) vv[u] = *(const float4*)&Vs[kk + u][d0];
#pragma unroll
            for (int j = 0; j < 4; ++j) {
                acc[j][0] += p[j].x * vv[0].x + p[j].y * vv[1].x + p[j].z * vv[2].x + p[j].w * vv[3].x;
                acc[j][1] += p[j].x * vv[0].y + p[j].y * vv[1].y + p[j].z * vv[2].y + p[j].w * vv[3].y;
                acc[j][2] += p[j].x * vv[0].z + p[j].y * vv[1].z + p[j].z * vv[2].z + p[j].w * vv[3].z;
                acc[j][3] += p[j].x * vv[0].w + p[j].y * vv[1].w + p[j].z * vv[2].w + p[j].w * vv[3].w;
            }
        }
    }
#pragma unroll
    for (int j = 0; j < 4; ++j) {
        const float iv = 1.0f / l_i[j];
        float4 r;
        r.x = acc[j][0] * iv; r.y = acc[j][1] * iv; r.z = acc[j][2] * iv; r.w = acc[j][3] * iv;
        *(float4*)&Out[((size_t)(b * S + q0 + qr0 + j)) * E + h * D + d0] = r;
    }
}

extern "C" void kernel_launch(void* const* d_in, const int* in_sizes, int n_in,
                              void* d_out, int out_size, void* d_ws, size_t ws_size,
                              hipStream_t stream) {
    (void)in_sizes; (void)n_in; (void)out_size;
    const float* q = (const float*)d_in[0];
    const float* k = (const float*)d_in[1];
    const float* v = (const float*)d_in[2];
    const int*   m = (const int*)d_in[3];
    float* out = (float*)d_out;

    if (ws_size >= WS_NEED) {
        char* ws = (char*)d_ws;
        prep_all<<<2048, 256, 0, stream>>>(k, v, m, ws);
        fa_mfma<<<512, 512, 0, stream>>>(q, ws, out);
    } else {
        fa_fp32<<<B * H * (S / QT), 256, 0, stream>>>(q, k, v, m, out);
    }
}